// Round 1
// baseline (18328.703 us; speedup 1.0000x reference)
//
#include <hip/hip_runtime.h>
#include <math.h>

#define SS 512
#define AANG 60
#define DDET 729
#define NPIX (SS*SS)        // 262144
#define NSIN (AANG*DDET)    // 43740
#define NTAPS 1457

// ---------------- trig table: ca[60], sa[60] ----------------
__global__ void trig_kernel(const float* __restrict__ theta, float* __restrict__ trig){
  int a = threadIdx.x;
  if (a < AANG){ trig[a] = cosf(theta[a]); trig[AANG+a] = sinf(theta[a]); }
}

// ---------------- ramp-filter taps (exact irfft of 2*rfftfreq(2048), folded pi/120) --------
// x[m] = ( (1/512) * sum_{k=1}^{1023} k*cos(2*pi*k*m/2048) + (-1)^m ) / 2048
// circular conv == linear conv here since 2*729-1 = 1457 < 2048 (zero padding)
__global__ void taps_kernel(float* __restrict__ taps){
  __shared__ double red[256];
  int m  = blockIdx.x;      // 0..1456
  int mm = m - 728;         // -728..728
  double s = 0.0;
  for (int k = 1 + (int)threadIdx.x; k <= 1023; k += 256){
    int phase = (k*mm) & 2047;   // exact integer mod 2048 (works for negative)
    s += (double)k * cos((double)phase * (M_PI/1024.0));
  }
  red[threadIdx.x] = s;
  __syncthreads();
  for (int off=128; off; off>>=1){
    if ((int)threadIdx.x < off) red[threadIdx.x] += red[threadIdx.x+off];
    __syncthreads();
  }
  if (threadIdx.x==0){
    double x = (red[0]*(1.0/512.0) + ((mm & 1) ? -1.0 : 1.0)) / 2048.0;
    taps[m] = (float)(x * (M_PI/120.0));   // fold FBP normalization pi/(2*60)
  }
}

// ---------------- radon forward: img[512x512] -> out[60x729] ----------------
// one wave per (a,d); lanes split t=0..511 (8 each), shuffle reduce
__global__ void radon_fwd_kernel(const float* __restrict__ img, const float* __restrict__ trig,
                                 float* __restrict__ out){
  int gid  = blockIdx.x*4 + ((int)threadIdx.x >> 6);
  int lane = (int)threadIdx.x & 63;
  if (gid >= NSIN) return;
  int a = gid / DDET;
  int d = gid - a*DDET;
  float ca = trig[a], sa = trig[AANG+a];
  float sd = (float)d - 364.0f;
  float acc = 0.f;
  for (int t = lane; t < SS; t += 64){
    float tp  = (float)t - 255.5f;
    float row = sd*sa + tp*ca + 255.5f;
    float col = sd*ca - tp*sa + 255.5f;
    float rf = floorf(row), cf = floorf(col);
    int r0 = (int)rf, c0 = (int)cf;
    int r1 = r0+1,    c1 = c0+1;
    float fr = row - rf, fc = col - cf;
    bool r0ok = (r0>=0 && r0<SS), r1ok = (r1>=0 && r1<SS);
    bool c0ok = (c0>=0 && c0<SS), c1ok = (c1>=0 && c1<SS);
    float v00 = (r0ok && c0ok) ? img[r0*SS+c0] : 0.f;
    float v01 = (r0ok && c1ok) ? img[r0*SS+c1] : 0.f;
    float v10 = (r1ok && c0ok) ? img[r1*SS+c0] : 0.f;
    float v11 = (r1ok && c1ok) ? img[r1*SS+c1] : 0.f;
    acc += (1.f-fr)*((1.f-fc)*v00 + fc*v01) + fr*((1.f-fc)*v10 + fc*v11);
  }
  for (int off=32; off; off>>=1) acc += __shfl_down(acc, off);
  if (lane==0) out[gid] = acc;
}

// ---------------- ramp filter: direct 1457-tap conv along detector axis ----------------
__global__ void filter_kernel(const float* __restrict__ h0, const float* __restrict__ taps,
                              float* __restrict__ h1){
  int gid = blockIdx.x*blockDim.x + threadIdx.x;
  if (gid >= NSIN) return;
  int a = gid / DDET;
  int j = gid - a*DDET;
  const float* row = h0 + a*DDET;
  float acc = 0.f;
  for (int k=0;k<DDET;k++){
    acc += row[k] * taps[728 + j - k];
  }
  h1[gid] = acc;
}

// ---------------- backprojection: h1[60x729] -> out[512x512] ----------------
__global__ void backproj_kernel(const float* __restrict__ h1, const float* __restrict__ trig,
                                float* __restrict__ out){
  int pix = blockIdx.x*blockDim.x + threadIdx.x;
  if (pix >= NPIX) return;
  int y = pix >> 9, x = pix & 511;
  float X = (float)x - 255.5f;
  float Y = (float)y - 255.5f;
  float acc = 0.f;
  for (int a=0;a<AANG;a++){
    float sidx = X*trig[a] + Y*trig[AANG+a] + 364.0f;
    float ff = floorf(sidx);
    int i0 = (int)ff, i1 = i0+1;
    float fi = sidx - ff;
    float v0 = (i0>=0 && i0<DDET) ? h1[a*DDET+i0] : 0.f;
    float v1 = (i1>=0 && i1<DDET) ? h1[a*DDET+i1] : 0.f;
    acc += (1.f-fi)*v0 + fi*v1;
  }
  out[pix] = acc;
}

// ---------------- generic 3x3 SAME conv, NCHW, weights OIHW ----------------
// grid.y = output channel; weights for that channel staged in LDS
__global__ void conv3x3_kernel(const float* __restrict__ in, const float* __restrict__ wgt,
                               const float* __restrict__ bias, const float* __restrict__ prelu,
                               float* __restrict__ out, int Cin, int H, int W, int acc){
  __shared__ float sw[288];   // up to 32*9
  int o = blockIdx.y;
  int nw = Cin*9;
  for (int t=threadIdx.x; t<nw; t+=blockDim.x) sw[t] = wgt[o*nw+t];
  __syncthreads();
  int pix = blockIdx.x*blockDim.x + threadIdx.x;
  int HW = H*W;
  if (pix >= HW) return;
  int y = pix / W, x = pix - y*W;
  float s = bias[o];
  bool ym = y>0, yp = y<H-1, xm = x>0, xp = x<W-1;
  for (int i=0;i<Cin;i++){
    const float* ip = in + i*HW + pix;
    const float* wp = sw + i*9;
    if (ym){
      if (xm) s += wp[0]*ip[-W-1];
      s += wp[1]*ip[-W];
      if (xp) s += wp[2]*ip[-W+1];
    }
    if (xm) s += wp[3]*ip[-1];
    s += wp[4]*ip[0];
    if (xp) s += wp[5]*ip[1];
    if (yp){
      if (xm) s += wp[6]*ip[W-1];
      s += wp[7]*ip[W];
      if (xp) s += wp[8]*ip[W+1];
    }
  }
  if (prelu){ float aa = *prelu; s = (s>=0.f)? s : aa*s; }
  float* op = out + o*HW + pix;
  if (acc) *op += s; else *op = s;
}

// ---------------- concat assembly ----------------
__global__ void concat_dual(const float* __restrict__ h, const float* __restrict__ opf,
                            const float* __restrict__ g, float* __restrict__ out){
  int idx = blockIdx.x*blockDim.x + threadIdx.x;
  if (idx >= 7*NSIN) return;
  int ch = idx / NSIN, r = idx - ch*NSIN;
  float v;
  if (ch < 5) v = h[idx];
  else if (ch == 5) v = opf[r];
  else v = g[r];
  out[idx] = v;
}

__global__ void concat_prim(const float* __restrict__ f, const float* __restrict__ bp,
                            float* __restrict__ out){
  int idx = blockIdx.x*blockDim.x + threadIdx.x;
  if (idx >= 6*NPIX) return;
  int ch = idx / NPIX, r = idx - ch*NPIX;
  out[idx] = (ch < 5) ? f[idx] : bp[r];
}

__global__ void write_out_kernel(const float* __restrict__ f0, float* __restrict__ out){
  int idx = blockIdx.x*blockDim.x + threadIdx.x;
  if (idx >= NPIX) return;
  float v = f0[idx];
  out[idx] = v; out[NPIX+idx] = v; out[2*NPIX+idx] = v;
}

extern "C" void kernel_launch(void* const* d_in, const int* in_sizes, int n_in,
                              void* d_out, int out_size, void* d_ws, size_t ws_size,
                              hipStream_t stream){
  // setup_inputs order:
  // 0 cond, 1 x0, 2 g, 3 theta, 4 theta_label,
  // 5 dw1, 6 db1, 7 da1, 8 dw2, 9 db2, 10 da2, 11 dw3, 12 db3,
  // 13 pw1, 14 pb1, 15 pa1, 16 pw2, 17 pb2, 18 pa2, 19 pw3, 20 pb3
  const float* g     = (const float*)d_in[2];
  const float* theta = (const float*)d_in[3];
  const float* dw1 = (const float*)d_in[5];
  const float* db1 = (const float*)d_in[6];
  const float* da1 = (const float*)d_in[7];
  const float* dw2 = (const float*)d_in[8];
  const float* db2 = (const float*)d_in[9];
  const float* da2 = (const float*)d_in[10];
  const float* dw3 = (const float*)d_in[11];
  const float* db3 = (const float*)d_in[12];
  const float* pw1 = (const float*)d_in[13];
  const float* pb1 = (const float*)d_in[14];
  const float* pa1 = (const float*)d_in[15];
  const float* pw2 = (const float*)d_in[16];
  const float* pb2 = (const float*)d_in[17];
  const float* pa2 = (const float*)d_in[18];
  const float* pw3 = (const float*)d_in[19];
  const float* pb3 = (const float*)d_in[20];

  float* ws     = (float*)d_ws;
  float* trig   = ws;                 // 120
  float* taps   = ws + 120;           // 1457
  float* h      = ws + 1577;          // 5*NSIN
  float* f      = h + 5*NSIN;         // 5*NPIX
  float* bp     = f + 5*NPIX;         // NPIX
  float* primIn = bp + NPIX;          // 6*NPIX
  float* primT1 = primIn + 6*NPIX;    // 32*NPIX
  float* primT2 = primT1 + 32*NPIX;   // 32*NPIX   (total ~80.6 MB)
  // dual-space temporaries aliased into primT1 (lifetimes disjoint)
  float* opf    = primT1;             // NSIN
  float* dualIn = opf + NSIN;         // 7*NSIN
  float* dualT1 = dualIn + 7*NSIN;    // 32*NSIN
  float* dualT2 = dualT1 + 32*NSIN;   // 32*NSIN
  float* h1     = dualT2 + 32*NSIN;   // NSIN

  // zero h and f (contiguous)
  hipMemsetAsync(h, 0, (size_t)(5*NSIN + 5*NPIX)*sizeof(float), stream);
  trig_kernel<<<1,64,0,stream>>>(theta, trig);
  taps_kernel<<<NTAPS,256,0,stream>>>(taps);

  for (int i=0;i<10;i++){
    // Op_f = radon_forward(f[ch1])
    radon_fwd_kernel<<<(NSIN+3)/4,256,0,stream>>>(f + NPIX, trig, opf);
    // dual block
    concat_dual<<<(7*NSIN+255)/256,256,0,stream>>>(h, opf, g, dualIn);
    conv3x3_kernel<<<dim3((NSIN+255)/256,32),256,0,stream>>>(dualIn, dw1+i*32*7*9, db1+(size_t)i*32, da1+i, dualT1, 7, AANG, DDET, 0);
    conv3x3_kernel<<<dim3((NSIN+255)/256,32),256,0,stream>>>(dualT1, dw2+i*32*32*9, db2+(size_t)i*32, da2+i, dualT2, 32, AANG, DDET, 0);
    conv3x3_kernel<<<dim3((NSIN+255)/256,5),256,0,stream>>>(dualT2, dw3+i*5*32*9, db3+(size_t)i*5, nullptr, h, 32, AANG, DDET, 1);
    // h1 = ramp_filter(h[ch0]); bp = backproject(h1)
    filter_kernel<<<(NSIN+255)/256,256,0,stream>>>(h, taps, h1);
    backproj_kernel<<<(NPIX+255)/256,256,0,stream>>>(h1, trig, bp);
    // primal block
    concat_prim<<<(6*NPIX+255)/256,256,0,stream>>>(f, bp, primIn);
    conv3x3_kernel<<<dim3(NPIX/256,32),256,0,stream>>>(primIn, pw1+i*32*6*9, pb1+(size_t)i*32, pa1+i, primT1, 6, SS, SS, 0);
    conv3x3_kernel<<<dim3(NPIX/256,32),256,0,stream>>>(primT1, pw2+i*32*32*9, pb2+(size_t)i*32, pa2+i, primT2, 32, SS, SS, 0);
    conv3x3_kernel<<<dim3(NPIX/256,5),256,0,stream>>>(primT2, pw3+i*5*32*9, pb3+(size_t)i*5, nullptr, f, 32, SS, SS, 1);
  }

  write_out_kernel<<<NPIX/256,256,0,stream>>>(f, (float*)d_out);
}

// Round 2
// 3336.332 us; speedup vs baseline: 5.4937x; 5.4937x over previous
//
#include <hip/hip_runtime.h>
#include <math.h>

#define SS 512
#define AANG 60
#define DDET 729
#define NPIX (SS*SS)        // 262144
#define NSIN (AANG*DDET)    // 43740
#define NTAPS 1457

// ---------------- trig table: ca[60], sa[60] ----------------
__global__ void trig_kernel(const float* __restrict__ theta, float* __restrict__ trig){
  int a = threadIdx.x;
  if (a < AANG){ trig[a] = cosf(theta[a]); trig[AANG+a] = sinf(theta[a]); }
}

// ---------------- ramp-filter taps (exact irfft of 2*rfftfreq(2048), folded pi/120) --------
__global__ void taps_kernel(float* __restrict__ taps){
  __shared__ double red[256];
  int m  = blockIdx.x;      // 0..1456
  int mm = m - 728;         // -728..728
  double s = 0.0;
  for (int k = 1 + (int)threadIdx.x; k <= 1023; k += 256){
    int phase = (k*mm) & 2047;   // exact integer mod 2048 (works for negative)
    s += (double)k * cos((double)phase * (M_PI/1024.0));
  }
  red[threadIdx.x] = s;
  __syncthreads();
  for (int off=128; off; off>>=1){
    if ((int)threadIdx.x < off) red[threadIdx.x] += red[threadIdx.x+off];
    __syncthreads();
  }
  if (threadIdx.x==0){
    double x = (red[0]*(1.0/512.0) + ((mm & 1) ? -1.0 : 1.0)) / 2048.0;
    taps[m] = (float)(x * (M_PI/120.0));   // fold FBP normalization pi/(2*60)
  }
}

// ---------------- weight transpose: [L][Cout][Cin][3][3] -> [L][Cin][9][Cout] ----------------
__global__ void transpose_w(const float* __restrict__ src, float* __restrict__ dst,
                            int Cout, int Cin){
  int idx = blockIdx.x*blockDim.x + threadIdx.x;
  int tot = 10*Cout*Cin*9;
  if (idx >= tot) return;
  int t = idx % 9; int r = idx/9;
  int i = r % Cin; r /= Cin;
  int o = r % Cout; int l = r/Cout;
  dst[((l*Cin+i)*9+t)*Cout+o] = src[idx];
}

// ---------------- radon forward: img[512x512] -> out[60x729] ----------------
__global__ void radon_fwd_kernel(const float* __restrict__ img, const float* __restrict__ trig,
                                 float* __restrict__ out){
  int gid  = blockIdx.x*4 + ((int)threadIdx.x >> 6);
  int lane = (int)threadIdx.x & 63;
  if (gid >= NSIN) return;
  int a = gid / DDET;
  int d = gid - a*DDET;
  float ca = trig[a], sa = trig[AANG+a];
  float sd = (float)d - 364.0f;
  float acc = 0.f;
  for (int t = lane; t < SS; t += 64){
    float tp  = (float)t - 255.5f;
    float row = sd*sa + tp*ca + 255.5f;
    float col = sd*ca - tp*sa + 255.5f;
    float rf = floorf(row), cf = floorf(col);
    int r0 = (int)rf, c0 = (int)cf;
    int r1 = r0+1,    c1 = c0+1;
    float fr = row - rf, fc = col - cf;
    bool r0ok = (r0>=0 && r0<SS), r1ok = (r1>=0 && r1<SS);
    bool c0ok = (c0>=0 && c0<SS), c1ok = (c1>=0 && c1<SS);
    float v00 = (r0ok && c0ok) ? img[r0*SS+c0] : 0.f;
    float v01 = (r0ok && c1ok) ? img[r0*SS+c1] : 0.f;
    float v10 = (r1ok && c0ok) ? img[r1*SS+c0] : 0.f;
    float v11 = (r1ok && c1ok) ? img[r1*SS+c1] : 0.f;
    acc += (1.f-fr)*((1.f-fc)*v00 + fc*v01) + fr*((1.f-fc)*v10 + fc*v11);
  }
  for (int off=32; off; off>>=1) acc += __shfl_down(acc, off);
  if (lane==0) out[gid] = acc;
}

// ---------------- ramp filter: direct 1457-tap conv along detector axis ----------------
__global__ void filter_kernel(const float* __restrict__ h0, const float* __restrict__ taps,
                              float* __restrict__ h1){
  int gid = blockIdx.x*blockDim.x + threadIdx.x;
  if (gid >= NSIN) return;
  int a = gid / DDET;
  int j = gid - a*DDET;
  const float* row = h0 + a*DDET;
  float acc = 0.f;
  for (int k=0;k<DDET;k++){
    acc += row[k] * taps[728 + j - k];
  }
  h1[gid] = acc;
}

// ---------------- backprojection: h1[60x729] -> out[512x512] ----------------
__global__ void backproj_kernel(const float* __restrict__ h1, const float* __restrict__ trig,
                                float* __restrict__ out){
  int pix = blockIdx.x*blockDim.x + threadIdx.x;
  if (pix >= NPIX) return;
  int y = pix >> 9, x = pix & 511;
  float X = (float)x - 255.5f;
  float Y = (float)y - 255.5f;
  float acc = 0.f;
  for (int a=0;a<AANG;a++){
    float sidx = X*trig[a] + Y*trig[AANG+a] + 364.0f;
    float ff = floorf(sidx);
    int i0 = (int)ff, i1 = i0+1;
    float fi = sidx - ff;
    float v0 = (i0>=0 && i0<DDET) ? h1[a*DDET+i0] : 0.f;
    float v1 = (i1>=0 && i1<DDET) ? h1[a*DDET+i1] : 0.f;
    acc += (1.f-fi)*v0 + fi*v1;
  }
  out[pix] = acc;
}

// ---------------- fast 3x3 SAME conv ----------------
// One thread per pixel computes ALL COUT output channels; loops over input
// channels (two concatenated sources). 9 guarded loads -> 9*COUT FMAs per
// input channel. Weights wt[(i*9+t)*COUT+o] are wave-uniform -> SGPR loads.
// W templated so neighbor loads use immediate offsets.
template<int COUT, int W>
__global__ __launch_bounds__(256) void conv3x3_fast(
    const float* __restrict__ in1, int Cin1,
    const float* __restrict__ in2, int Cin2,
    const float* __restrict__ wt,
    const float* __restrict__ bias, const float* __restrict__ prelu,
    float* __restrict__ out, int H, int accum)
{
  int HW = H*W;
  int pix = blockIdx.x*256 + (int)threadIdx.x;
  if (pix >= HW) return;
  int y = pix / W, x = pix - y*W;
  bool ym = y>0, yp = y<H-1, xm = x>0, xp = x<W-1;
  float acc[COUT];
  #pragma unroll
  for (int o=0;o<COUT;o++) acc[o] = bias[o];
  const float* wr = wt;
  for (int part=0; part<2; part++){
    const float* src = part ? in2 : in1;
    int nch = part ? Cin2 : Cin1;
    const float* ip = src + pix;
    for (int i=0;i<nch;i++, ip+=HW){
      float p0=0.f,p1=0.f,p2=0.f,p3=0.f,p5=0.f,p6=0.f,p7=0.f,p8=0.f;
      float p4 = ip[0];
      if (ym){ p1 = ip[-W]; if (xm) p0 = ip[-W-1]; if (xp) p2 = ip[-W+1]; }
      if (xm) p3 = ip[-1];
      if (xp) p5 = ip[1];
      if (yp){ p7 = ip[W]; if (xm) p6 = ip[W-1]; if (xp) p8 = ip[W+1]; }
      float p[9] = {p0,p1,p2,p3,p4,p5,p6,p7,p8};
      #pragma unroll
      for (int t=0;t<9;t++){
        float v = p[t];
        #pragma unroll
        for (int o=0;o<COUT;o++) acc[o] += v * wr[t*COUT+o];
      }
      wr += 9*COUT;
    }
  }
  float* op = out + pix;
  float aa = prelu ? *prelu : 0.f;
  #pragma unroll
  for (int o=0;o<COUT;o++){
    float s = acc[o];
    if (prelu) s = (s>=0.f) ? s : aa*s;
    if (accum) s += op[o*HW];
    op[o*HW] = s;
  }
}

__global__ void write_out_kernel(const float* __restrict__ f0, float* __restrict__ out){
  int idx = blockIdx.x*blockDim.x + threadIdx.x;
  if (idx >= NPIX) return;
  float v = f0[idx];
  out[idx] = v; out[NPIX+idx] = v; out[2*NPIX+idx] = v;
}

extern "C" void kernel_launch(void* const* d_in, const int* in_sizes, int n_in,
                              void* d_out, int out_size, void* d_ws, size_t ws_size,
                              hipStream_t stream){
  const float* g     = (const float*)d_in[2];
  const float* theta = (const float*)d_in[3];
  const float* dw1 = (const float*)d_in[5];
  const float* db1 = (const float*)d_in[6];
  const float* da1 = (const float*)d_in[7];
  const float* dw2 = (const float*)d_in[8];
  const float* db2 = (const float*)d_in[9];
  const float* da2 = (const float*)d_in[10];
  const float* dw3 = (const float*)d_in[11];
  const float* db3 = (const float*)d_in[12];
  const float* pw1 = (const float*)d_in[13];
  const float* pb1 = (const float*)d_in[14];
  const float* pa1 = (const float*)d_in[15];
  const float* pw2 = (const float*)d_in[16];
  const float* pb2 = (const float*)d_in[17];
  const float* pa2 = (const float*)d_in[18];
  const float* pw3 = (const float*)d_in[19];
  const float* pb3 = (const float*)d_in[20];

  float* ws     = (float*)d_ws;
  float* trig   = ws;                  // 128
  float* taps   = ws + 128;            // 1457 (pad to 1920)
  float* h      = ws + 2048;           // 5*NSIN
  float* f      = h + 5*NSIN;          // 5*NPIX
  float* bp     = f + 5*NPIX;          // NPIX
  float* dx     = bp + NPIX;           // 2*NSIN  (opf | g copy)
  float* opf    = dx;
  float* gcopy  = dx + NSIN;
  float* h1     = dx + 2*NSIN;         // NSIN
  float* primT1 = h1 + NSIN;           // 32*NPIX
  float* primT2 = primT1 + 32*NPIX;    // 32*NPIX
  // dual temporaries aliased into primT1 (lifetimes disjoint: dual convs of
  // iter i+1 run after primT1's last read in iter i)
  float* dualT1 = primT1;              // 32*NSIN
  float* dualT2 = dualT1 + 32*NSIN;    // 32*NSIN
  float* wspace = primT2 + 32*NPIX;    // transposed weights
  float* wtd1 = wspace;                // 10*7*9*32  = 20160
  float* wtd2 = wtd1 + 20160;          // 10*32*9*32 = 92160
  float* wtd3 = wtd2 + 92160;          // 10*32*9*5  = 14400
  float* wtp1 = wtd3 + 14400;          // 10*6*9*32  = 17280
  float* wtp2 = wtp1 + 17280;          // 92160
  float* wtp3 = wtp2 + 92160;          // 14400

  hipMemsetAsync(h, 0, (size_t)(5*NSIN + 5*NPIX)*sizeof(float), stream);
  hipMemcpyAsync(gcopy, g, (size_t)NSIN*sizeof(float), hipMemcpyDeviceToDevice, stream);
  trig_kernel<<<1,64,0,stream>>>(theta, trig);
  taps_kernel<<<NTAPS,256,0,stream>>>(taps);
  transpose_w<<<(20160+255)/256,256,0,stream>>>(dw1, wtd1, 32, 7);
  transpose_w<<<(92160+255)/256,256,0,stream>>>(dw2, wtd2, 32, 32);
  transpose_w<<<(14400+255)/256,256,0,stream>>>(dw3, wtd3, 5, 32);
  transpose_w<<<(17280+255)/256,256,0,stream>>>(pw1, wtp1, 32, 6);
  transpose_w<<<(92160+255)/256,256,0,stream>>>(pw2, wtp2, 32, 32);
  transpose_w<<<(14400+255)/256,256,0,stream>>>(pw3, wtp3, 5, 32);

  const int GD = (NSIN+255)/256;   // dual grid (171)
  const int GP = NPIX/256;         // primal grid (1024)

  for (int i=0;i<10;i++){
    // Op_f = radon_forward(f[ch1])
    radon_fwd_kernel<<<(NSIN+3)/4,256,0,stream>>>(f + NPIX, trig, opf);
    // dual block: in = [h(5) | opf(1) g(1)]
    conv3x3_fast<32,DDET><<<GD,256,0,stream>>>(h, 5, dx, 2,      wtd1+i*7*9*32,  db1+(size_t)i*32, da1+i, dualT1, AANG, 0);
    conv3x3_fast<32,DDET><<<GD,256,0,stream>>>(dualT1, 32, nullptr, 0, wtd2+i*32*9*32, db2+(size_t)i*32, da2+i, dualT2, AANG, 0);
    conv3x3_fast<5,DDET><<<GD,256,0,stream>>>(dualT2, 32, nullptr, 0, wtd3+i*32*9*5,  db3+(size_t)i*5,  nullptr, h, AANG, 1);
    // h1 = ramp_filter(h[ch0]); bp = backproject(h1)
    filter_kernel<<<GD,256,0,stream>>>(h, taps, h1);
    backproj_kernel<<<GP,256,0,stream>>>(h1, trig, bp);
    // primal block: in = [f(5) | bp(1)]
    conv3x3_fast<32,SS><<<GP,256,0,stream>>>(f, 5, bp, 1,        wtp1+i*6*9*32,  pb1+(size_t)i*32, pa1+i, primT1, SS, 0);
    conv3x3_fast<32,SS><<<GP,256,0,stream>>>(primT1, 32, nullptr, 0, wtp2+i*32*9*32, pb2+(size_t)i*32, pa2+i, primT2, SS, 0);
    conv3x3_fast<5,SS><<<GP,256,0,stream>>>(primT2, 32, nullptr, 0, wtp3+i*32*9*5,  pb3+(size_t)i*5,  nullptr, f, SS, 1);
  }

  write_out_kernel<<<GP,256,0,stream>>>(f, (float*)d_out);
}